// Round 7
// baseline (114.538 us; speedup 1.0000x reference)
//
#include <hip/hip_runtime.h>
#include <math.h>

#define NB 4
#define CH 256
#define NHEADS 4
#define HC 64
#define NT 2304   // 48*48
#define NCH 36    // key chunks of 64

typedef _Float16 f16;
typedef _Float16 f16x4 __attribute__((ext_vector_type(4)));
typedef _Float16 f16x8 __attribute__((ext_vector_type(8)));
typedef float f32x4 __attribute__((ext_vector_type(4)));
typedef float f32x16 __attribute__((ext_vector_type(16)));

#define MFMA16(a, b, c) __builtin_amdgcn_mfma_f32_16x16x32_f16(a, b, c, 0, 0, 0)
#define MFMA32(a, b, c) __builtin_amdgcn_mfma_f32_32x32x16_f16(a, b, c, 0, 0, 0)

__device__ __forceinline__ void gload_lds16(const void* g, void* l) {
    __builtin_amdgcn_global_load_lds(
        (const __attribute__((address_space(1))) unsigned int*)g,
        (__attribute__((address_space(3))) unsigned int*)l, 16, 0, 0);
}

__device__ __forceinline__ unsigned pkh(float a, float b) {
    auto r = __builtin_amdgcn_cvt_pkrtz(a, b);   // __fp16 ext_vector(2)
    return __builtin_bit_cast(unsigned, r);
}
// v_permlane32_swap_b32: new_a = [a.lo32 | b.lo32_old], new_b = [a.hi32_old | b.hi32]
__device__ __forceinline__ void swap32(unsigned& a, unsigned& b) {
    asm volatile("v_permlane32_swap_b32 %0, %1" : "+v"(a), "+v"(b));
}

// ---------------------------------------------------------------------------
// x [b][c][n] f32  ->  Xt [b][n][c] f16      (unchanged from R5)
// ---------------------------------------------------------------------------
__global__ __launch_bounds__(256) void xpose_f32_to_f16(
    const float* __restrict__ X, f16* __restrict__ Xt)
{
    __shared__ f16 T[64][68];
    const int t = threadIdx.x;
    const int n0 = blockIdx.x * 64, c0 = blockIdx.y * 64, b = blockIdx.z;

#pragma unroll
    for (int i = 0; i < 4; ++i) {
        const int lin = i * 256 + t;
        const int c = lin >> 4, n4 = (lin & 15) << 2;
        const float4 v = *reinterpret_cast<const float4*>(
            &X[((size_t)(b * CH + c0 + c)) * NT + n0 + n4]);
        f16x4 hv = {(f16)v.x, (f16)v.y, (f16)v.z, (f16)v.w};
        *reinterpret_cast<f16x4*>(&T[c][n4]) = hv;
    }
    __syncthreads();
    {
        const int n = t >> 2, cs = (t & 3) << 4;
        f16x8 o0, o1;
#pragma unroll
        for (int k = 0; k < 8; ++k) o0[k] = T[cs + k][n];
#pragma unroll
        for (int k = 0; k < 8; ++k) o1[k] = T[cs + 8 + k][n];
        f16* dst = &Xt[((size_t)(b * NT + n0 + n)) * CH + c0 + cs];
        *reinterpret_cast<f16x8*>(dst) = o0;
        *reinterpret_cast<f16x8*>(dst + 8) = o1;
    }
}

// ---------------------------------------------------------------------------
// Fused K/Q/V projection (unchanged from R5). grid (36, 3, 4).
// ---------------------------------------------------------------------------
__global__ __launch_bounds__(256) void proj_qkv_mfma(
    const float* __restrict__ wk, const float* __restrict__ bk,
    const float* __restrict__ wq, const float* __restrict__ bq,
    const float* __restrict__ wv, const float* __restrict__ bv,
    const f16* __restrict__ Xt,
    f16* __restrict__ Kt, f16* __restrict__ Qt, f16* __restrict__ Vg)
{
    const int t = threadIdx.x, l = t & 63, w = t >> 6;
    const int lm = l & 15, lg = l >> 4;
    const int n0 = blockIdx.x * 64;
    const int sel = blockIdx.y;
    const int b = blockIdx.z;

    const float* W  = sel == 0 ? wk : (sel == 1 ? wq : wv);
    const float* Bi = sel == 0 ? bk : (sel == 1 ? bq : bv);

    f32x4 acc[4][4] = {};

#pragma unroll 2
    for (int ks = 0; ks < 8; ++ks) {
        f16x8 bf[4];
#pragma unroll
        for (int nt = 0; nt < 4; ++nt)
            bf[nt] = *reinterpret_cast<const f16x8*>(
                &Xt[((size_t)(b * NT + n0 + nt * 16 + lm)) * CH + ks * 32 + lg * 8]);
#pragma unroll
        for (int h = 0; h < 4; ++h) {
            const float* wp = &W[(size_t)(h * 64 + w * 16 + lm) * CH + ks * 32 + lg * 8];
            const float4 wa = *reinterpret_cast<const float4*>(wp);
            const float4 wb = *reinterpret_cast<const float4*>(wp + 4);
            const f16x8 a = {(f16)wa.x, (f16)wa.y, (f16)wa.z, (f16)wa.w,
                             (f16)wb.x, (f16)wb.y, (f16)wb.z, (f16)wb.w};
#pragma unroll
            for (int nt = 0; nt < 4; ++nt)
                acc[h][nt] = MFMA16(a, bf[nt], acc[h][nt]);
        }
    }

    const int c_base = w * 16 + lg * 4;
#pragma unroll
    for (int h = 0; h < 4; ++h) {
        const float4 b4 = *reinterpret_cast<const float4*>(&Bi[h * 64 + c_base]);
        const float bb[4] = {b4.x, b4.y, b4.z, b4.w};
        if (sel < 2) {
            f16* Out = sel == 0 ? Kt : Qt;
#pragma unroll
            for (int nt = 0; nt < 4; ++nt) {
                const int n = n0 + nt * 16 + lm;
                f16x4 o = {(f16)(acc[h][nt][0] + bb[0]), (f16)(acc[h][nt][1] + bb[1]),
                           (f16)(acc[h][nt][2] + bb[2]), (f16)(acc[h][nt][3] + bb[3])};
                *reinterpret_cast<f16x4*>(
                    &Out[((size_t)((b * NHEADS + h) * NT + n)) * HC + c_base]) = o;
            }
        } else {
#pragma unroll
            for (int nt = 0; nt < 4; ++nt) {
                const int n = n0 + nt * 16 + lm;
#pragma unroll
                for (int r = 0; r < 4; ++r)
                    Vg[((size_t)((b * NHEADS + h) * HC + c_base + r)) * NT + n] =
                        (f16)(acc[h][nt][r] + bb[r]);
            }
        }
    }
}

// ---------------------------------------------------------------------------
// Flash attention, 32x32x16 MFMA, 32 queries/wave, 2-wave blocks.
// In-register P via cvt_pkrtz + v_permlane32_swap (no P LDS roundtrip).
// K/V LDS double-buffer, swizzled global_load_lds staging (wave0 K, wave1 V).
// Defer-max (THR=8): skip rescale while chunk max stays within 8 of running.
// XCD decode as R5: xcd = bid&7 owns 2 (b,h) pairs -> L2-resident K/V.
// grid 576, block 128.
// ---------------------------------------------------------------------------
__global__ __launch_bounds__(128) void attn_mfma_32q(
    const f16* __restrict__ Kt, const f16* __restrict__ Qt,
    const f16* __restrict__ Vg, f16* __restrict__ Ot)
{
    __shared__ f16 KS[2][64 * 64];   // [buf][key][64c], 16B units swizzled
    __shared__ f16 VS[2][64 * 64];   // [buf][c][64k]

    const int t = threadIdx.x, l = t & 63, w = t >> 6;
    const int col = l & 31, hi = l >> 5;

    const int bid = blockIdx.x;
    const int xcd = bid & 7, idx = bid >> 3;
    const int bh  = 2 * xcd + (idx >= NCH ? 1 : 0);
    const int qt  = idx >= NCH ? idx - NCH : idx;
    const int b = bh >> 2, h = bh & 3;
    const int m0 = qt * 64;

    const size_t bhs = (size_t)(b * NHEADS + h);
    const f16* Kb = Kt + bhs * NT * HC;   // [n][64c] rows of 128 B
    const f16* Qb = Qt + bhs * NT * HC;
    const f16* Vb = Vg + bhs * HC * NT;   // [c][n]

    const int srow = l >> 3, su = l & 7, sx = su ^ srow;

    // resident Q B-frags: col = l&31 = query, k = cs*16 + hi*8 + j
    const int q = m0 + w * 32 + col;
    f16x8 qf[4];
#pragma unroll
    for (int cs = 0; cs < 4; ++cs)
        qf[cs] = *reinterpret_cast<const f16x8*>(
            &Qb[(size_t)q * HC + cs * 16 + hi * 8]);

    const f32x16 Z16 = {0,0,0,0,0,0,0,0,0,0,0,0,0,0,0,0};
    f32x16 acc0 = Z16, acc1 = Z16;
    float m_run = -3.0e38f, l_run = 0.0f;

    auto stage = [&](int kc, int buf) {
        if (w == 0) {          // K chunk: 64 rows x 128B contiguous
            const char* src = (const char*)(Kb + (size_t)kc * HC);
            char* dst = (char*)&KS[buf][0];
#pragma unroll
            for (int g = 0; g < 8; ++g)
                gload_lds16(src + (size_t)(g * 8 + srow) * 128 + (sx << 4),
                            dst + g * 1024);
        } else {               // V chunk: 64 c-rows, stride NT*2
            const char* src = (const char*)Vb + (size_t)kc * 2;
            char* dst = (char*)&VS[buf][0];
#pragma unroll
            for (int g = 0; g < 8; ++g)
                gload_lds16(src + (size_t)(g * 8 + srow) * (NT * 2) + (sx << 4),
                            dst + g * 1024);
        }
    };

    // swizzled LDS read: 16B unit `u` of row -> stored at u ^ (row&7)
    auto rd = [&](const f16* base, int row, int u) -> f16x8 {
        return *reinterpret_cast<const f16x8*>(
            base + row * 64 + ((u ^ (row & 7)) << 3));
    };

    stage(0, 0);
    __syncthreads();

    for (int i = 0; i < NCH; ++i) {
        const int cur = i & 1;
        if (i + 1 < NCH) stage((i + 1) * 64, cur ^ 1);

        const f16* Kc = &KS[cur][0];
        const f16* Vc = &VS[cur][0];

        // ---- QK^T: S[key][query]; A=K rows(l&31), B=Q ------------------
        f32x16 s0 = Z16, s1 = Z16;
#pragma unroll
        for (int cs = 0; cs < 4; ++cs) {
            const f16x8 k0 = rd(Kc, col,      cs * 2 + hi);
            const f16x8 k1 = rd(Kc, 32 + col, cs * 2 + hi);
            s0 = MFMA32(k0, qf[cs], s0);
            s1 = MFMA32(k1, qf[cs], s1);
        }

        // ---- softmax over this chunk (query = col) ----------------------
        float cm = -3.0e38f;
#pragma unroll
        for (int r = 0; r < 16; ++r) {
            cm = fmaxf(cm, s0[r]);
            cm = fmaxf(cm, s1[r]);
        }
        cm = fmaxf(cm, __shfl_xor(cm, 32));
        if (!__all(cm <= m_run + 8.0f)) {     // defer-max, THR=8
            const float mN = fmaxf(m_run, cm);
            const float fac = __expf(m_run - mN);
#pragma unroll
            for (int r = 0; r < 16; ++r) { acc0[r] *= fac; acc1[r] *= fac; }
            l_run *= fac;
            m_run = mN;
        }
        float p0[16], p1[16], ps = 0.0f;
#pragma unroll
        for (int r = 0; r < 16; ++r) {
            p0[r] = __expf(s0[r] - m_run); ps += p0[r];
            p1[r] = __expf(s1[r] - m_run); ps += p1[r];
        }
        l_run += ps;   // per-lane partial; cross-lane reduce deferred to end

        // ---- P -> f16 B-frags in-register (pkrtz + permlane32_swap) -----
        // C rows per lane: key = kt*32 + (r&3)+8*(r>>2)+4*hi. B-frag for
        // kstep s needs keys s*16 + hi*8 + j: pairs (X,U),(Y,V) swap across
        // lane±32 to assemble [X',Y',U',V'].
        unsigned a0[8], a1[8];
#pragma unroll
        for (int j = 0; j < 8; ++j) {
            a0[j] = pkh(p0[2 * j], p0[2 * j + 1]);
            a1[j] = pkh(p1[2 * j], p1[2 * j + 1]);
        }
        swap32(a0[0], a0[2]); swap32(a0[1], a0[3]);   // kt0, keys 0-15
        swap32(a0[4], a0[6]); swap32(a0[5], a0[7]);   // kt0, keys 16-31
        swap32(a1[0], a1[2]); swap32(a1[1], a1[3]);   // kt1, keys 32-47
        swap32(a1[4], a1[6]); swap32(a1[5], a1[7]);   // kt1, keys 48-63
        union BU { unsigned u[4]; f16x8 v; };
        BU fr[4];
        fr[0].u[0] = a0[0]; fr[0].u[1] = a0[1]; fr[0].u[2] = a0[2]; fr[0].u[3] = a0[3];
        fr[1].u[0] = a0[4]; fr[1].u[1] = a0[5]; fr[1].u[2] = a0[6]; fr[1].u[3] = a0[7];
        fr[2].u[0] = a1[0]; fr[2].u[1] = a1[1]; fr[2].u[2] = a1[2]; fr[2].u[3] = a1[3];
        fr[3].u[0] = a1[4]; fr[3].u[1] = a1[5]; fr[3].u[2] = a1[6]; fr[3].u[3] = a1[7];

        // ---- O += V @ P: A=V rows(c), B=P --------------------------------
#pragma unroll
        for (int ks = 0; ks < 4; ++ks) {
            const f16x8 v0 = rd(Vc, col,      ks * 2 + hi);
            const f16x8 v1 = rd(Vc, 32 + col, ks * 2 + hi);
            acc0 = MFMA32(v0, fr[ks].v, acc0);
            acc1 = MFMA32(v1, fr[ks].v, acc1);
        }

        __syncthreads();   // buf[cur] free; prefetch into buf[cur^1] drained
    }

    // ---- epilogue: normalize, store Ot[b][n=q][h*64 + c] -----------------
    const float lf = l_run + __shfl_xor(l_run, 32);
    const float inv = 1.0f / lf;
    f16* Ob = &Ot[((size_t)(b * NT + q)) * CH + h * HC];
#pragma unroll
    for (int rq = 0; rq < 4; ++rq) {
        const int c0 = rq * 8 + hi * 4;     // row = (r&3) + 8*(r>>2) + 4*hi
        f16x4 o0 = {(f16)(acc0[rq * 4 + 0] * inv), (f16)(acc0[rq * 4 + 1] * inv),
                    (f16)(acc0[rq * 4 + 2] * inv), (f16)(acc0[rq * 4 + 3] * inv)};
        f16x4 o1 = {(f16)(acc1[rq * 4 + 0] * inv), (f16)(acc1[rq * 4 + 1] * inv),
                    (f16)(acc1[rq * 4 + 2] * inv), (f16)(acc1[rq * 4 + 3] * inv)};
        *reinterpret_cast<f16x4*>(Ob + c0) = o0;
        *reinterpret_cast<f16x4*>(Ob + 32 + c0) = o1;
    }
}

// ---------------------------------------------------------------------------
// Final conv1x1 (unchanged from R5). grid (36, 4, 4).
// ---------------------------------------------------------------------------
__global__ __launch_bounds__(256) void out_gemm_mfma(
    const float* __restrict__ wo, const float* __restrict__ bo,
    const f16* __restrict__ Ot, float* __restrict__ Y)
{
    const int t = threadIdx.x, l = t & 63, w = t >> 6;
    const int lm = l & 15, lg = l >> 4;
    const int n0 = blockIdx.x * 64;
    const int o0 = blockIdx.y * 64;
    const int b = blockIdx.z;

    f32x4 acc[4] = {{0.f,0.f,0.f,0.f},{0.f,0.f,0.f,0.f},
                    {0.f,0.f,0.f,0.f},{0.f,0.f,0.f,0.f}};
    const int o_row = o0 + w * 16 + lm;

#pragma unroll
    for (int ks = 0; ks < 8; ++ks) {
        const float* wp = &wo[(size_t)o_row * CH + ks * 32 + lg * 8];
        const float4 wa = *reinterpret_cast<const float4*>(wp);
        const float4 wb = *reinterpret_cast<const float4*>(wp + 4);
        const f16x8 a = {(f16)wa.x, (f16)wa.y, (f16)wa.z, (f16)wa.w,
                         (f16)wb.x, (f16)wb.y, (f16)wb.z, (f16)wb.w};
#pragma unroll
        for (int nt = 0; nt < 4; ++nt) {
            const f16x8 bf = *reinterpret_cast<const f16x8*>(
                &Ot[((size_t)(b * NT + n0 + nt * 16 + lm)) * CH + ks * 32 + lg * 8]);
            acc[nt] = MFMA16(a, bf, acc[nt]);
        }
    }

    const int ob = o0 + w * 16 + lg * 4;
    const float4 bias4 = *reinterpret_cast<const float4*>(&bo[ob]);
    const float bb[4] = {bias4.x, bias4.y, bias4.z, bias4.w};
#pragma unroll
    for (int nt = 0; nt < 4; ++nt) {
        const int n = n0 + nt * 16 + lm;
#pragma unroll
        for (int r = 0; r < 4; ++r)
            Y[((size_t)(b * CH + ob + r)) * NT + n] = acc[nt][r] + bb[r];
    }
}

// ---------------------------------------------------------------------------
extern "C" void kernel_launch(void* const* d_in, const int* in_sizes, int n_in,
                              void* d_out, int out_size, void* d_ws, size_t ws_size,
                              hipStream_t stream) {
    (void)in_sizes; (void)n_in; (void)out_size; (void)ws_size;
    const float* x  = (const float*)d_in[0];
    const float* wk = (const float*)d_in[1];
    const float* bk = (const float*)d_in[2];
    const float* wq = (const float*)d_in[3];
    const float* bq = (const float*)d_in[4];
    const float* wv = (const float*)d_in[5];
    const float* bv = (const float*)d_in[6];
    const float* wo = (const float*)d_in[7];
    const float* bo = (const float*)d_in[8];
    float* out = (float*)d_out;

    const size_t SZ = (size_t)NB * NT * CH;   // halves per tensor
    f16* Xt = (f16*)d_ws;        // [b][n][c]
    f16* Kt = Xt + SZ;           // [b][h][n][c]
    f16* Qt = Kt + SZ;           // [b][h][n][c]
    f16* Vg = Qt + SZ;           // [b][h][c][n]
    f16* Ot = Vg + SZ;           // [b][n][c]

    xpose_f32_to_f16<<<dim3(36, 4, 4), 256, 0, stream>>>(x, Xt);
    proj_qkv_mfma<<<dim3(36, 3, 4), 256, 0, stream>>>(
        wk, bk, wq, bq, wv, bv, Xt, Kt, Qt, Vg);
    attn_mfma_32q<<<dim3(576), 128, 0, stream>>>(Kt, Qt, Vg, Ot);
    out_gemm_mfma<<<dim3(36, 4, 4), 256, 0, stream>>>(wo, bo, Ot, out);
}